// Round 7
// baseline (221.292 us; speedup 1.0000x reference)
//
#include <hip/hip_runtime.h>
#include <hip/hip_bf16.h>
#include <stdint.h>

// Problem constants
#define B_   4
#define S_   2048
#define E_   1024
#define H_   16
#define D_   64
#define M_   (B_ * S_)     // 8192 rows
#define E3_  (3 * E_)      // 3072

#define QSCALE 0.18033688011112042f  // 0.125 * log2(e)

typedef __bf16 bf16_t;
typedef bf16_t bf16x8 __attribute__((ext_vector_type(8)));
typedef float  f32x4  __attribute__((ext_vector_type(4)));
typedef float  f32x16 __attribute__((ext_vector_type(16)));

__device__ __forceinline__ ushort f2bf(float f) {
  union { float f; uint32_t u; } v; v.f = f;
  uint32_t r = v.u + 0x7fffu + ((v.u >> 16) & 1u);
  return (ushort)(r >> 16);
}

__device__ __forceinline__ unsigned cvtpk(float lo, float hi_) {
  unsigned d;
  asm("v_cvt_pk_bf16_f32 %0, %1, %2" : "=v"(d) : "v"(lo), "v"(hi_));
  return d;
}

__device__ __forceinline__ void gload_lds16(const void* g, void* l) {
  __builtin_amdgcn_global_load_lds((const __attribute__((address_space(1))) void*)g,
                                   (__attribute__((address_space(3))) void*)l,
                                   16, 0, 0);
}

// ---------------------------------------------------------------- cvt f32->bf16 (optional row-scale)
__global__ __launch_bounds__(256) void cvt_f32_bf16(const float* __restrict__ in,
                                                    ushort* __restrict__ out, int n4,
                                                    int scale_row4, float scale) {
  int i = blockIdx.x * blockDim.x + threadIdx.x;
  if (i < n4) {
    float4 v = reinterpret_cast<const float4*>(in)[i];
    if (i < scale_row4) { v.x *= scale; v.y *= scale; v.z *= scale; v.w *= scale; }
    ushort4 o;
    o.x = f2bf(v.x); o.y = f2bf(v.y); o.z = f2bf(v.z); o.w = f2bf(v.w);
    reinterpret_cast<ushort4*>(out)[i] = o;
  }
}

// ---------------------------------------------------------------- QKV GEMM, 256x256 tile, 8-phase
// A: [M_][1024] bf16. Bt: [3072][1024] bf16. Epilogue: cols<2048 -> qk[row][2048] bf16;
// cols>=2048 -> vT[(b*1024 + col-2048)][2048] (s-contiguous); q-bias scaled by QSCALE.
// 512 thr = 8 waves (2M x 4N); wave out 128x64; BK=64; LDS 128KB dbuf; T2 swizzle;
// per-tile: 4 quadrant phases {ds_read | stage-next | barrier | lgkm0 | prio1 16xMFMA prio0 | barrier},
// vmcnt(0) only at tile boundary (issued-early loads). XCD-bijective block swizzle (384%8==0).
__global__ __launch_bounds__(512) void gemm_qkv_256(const ushort* __restrict__ A,
                                                    const ushort* __restrict__ Bt,
                                                    const float* __restrict__ bias,
                                                    ushort* __restrict__ qkout,
                                                    ushort* __restrict__ vTout) {
  __shared__ __align__(16) ushort As[2][256 * 64];
  __shared__ __align__(16) ushort Bs[2][256 * 64];

  const int tid = threadIdx.x;
  const int lane = tid & 63, wid = tid >> 6;
  const int wr = wid >> 2, wc = wid & 3;

  const int b0 = blockIdx.x;
  const int nb = (b0 & 7) * 48 + (b0 >> 3);   // 384 blocks -> 48/XCD contiguous
  const int bm = (nb / 12) * 256, bn = (nb % 12) * 256;

  // ---- staging: each wave stages its own A-half (4KB/tile) + B-quarter share (4KB/tile)
  const int l8 = lane >> 3;                 // 0..7
  const int scol8 = (lane & 7) ^ l8;        // pre-swizzled global col8 (T2 involution)
  const ushort* aSrc = A  + (size_t)(bm + wr * 128 + wc * 32 + l8) * 1024 + scol8 * 8;
  const ushort* bSrc = Bt + (size_t)(bn + wc * 64 + wr * 32 + l8) * 1024 + scol8 * 8;

#define STAGE8(T, BI)                                                                        \
  do {                                                                                       \
    _Pragma("unroll")                                                                        \
    for (int j = 0; j < 4; ++j)                                                              \
      gload_lds16(aSrc + (T) * 64 + j * 8192, (void*)&As[BI][(wr * 128 + wc * 32 + j * 8) * 64]); \
    _Pragma("unroll")                                                                        \
    for (int j = 0; j < 4; ++j)                                                              \
      gload_lds16(bSrc + (T) * 64 + j * 8192, (void*)&Bs[BI][(wc * 64 + wr * 32 + j * 8) * 64]); \
  } while (0)

  // ---- fragment read addressing (swizzled slots)
  const int arow = wr * 128 + (lane & 15);
  const int brow = wc * 64 + (lane & 15);
  const int sl0 = (((lane >> 4) + 0) ^ (lane & 7)) * 16;   // kh=0 16B slot
  const int sl1 = (((lane >> 4) + 4) ^ (lane & 7)) * 16;   // kh=1 16B slot

#define LDA(dst, m, p)                                                                     \
  do {                                                                                     \
    dst[0] = *(const bf16x8*)((const char*)&As[p][0] + (arow + (m) * 16) * 128 + sl0);     \
    dst[1] = *(const bf16x8*)((const char*)&As[p][0] + (arow + (m) * 16) * 128 + sl1);     \
  } while (0)
#define LDB(dst, n, p)                                                                     \
  do {                                                                                     \
    dst[0] = *(const bf16x8*)((const char*)&Bs[p][0] + (brow + (n) * 16) * 128 + sl0);     \
    dst[1] = *(const bf16x8*)((const char*)&Bs[p][0] + (brow + (n) * 16) * 128 + sl1);     \
  } while (0)

#define BARRIER_FENCE()                        \
  do {                                         \
    __builtin_amdgcn_s_barrier();              \
    __builtin_amdgcn_sched_barrier(0);         \
  } while (0)

#define MFMA16(MB, NB)                                                                      \
  do {                                                                                      \
    __builtin_amdgcn_s_setprio(1);                                                          \
    _Pragma("unroll")                                                                       \
    for (int m = 0; m < 4; ++m)                                                             \
      _Pragma("unroll")                                                                     \
      for (int n = 0; n < 2; ++n)                                                           \
        _Pragma("unroll")                                                                   \
        for (int kh = 0; kh < 2; ++kh)                                                      \
          acc[(MB) + m][(NB) + n] = __builtin_amdgcn_mfma_f32_16x16x32_bf16(                \
              af[m][kh], bf[n][kh], acc[(MB) + m][(NB) + n], 0, 0, 0);                      \
    __builtin_amdgcn_s_setprio(0);                                                          \
  } while (0)

  f32x4 acc[8][4] = {};
  bf16x8 af[4][2], bf[2][2];

  STAGE8(0, 0);
  asm volatile("s_waitcnt vmcnt(0)" ::: "memory");
  BARRIER_FENCE();

  for (int t = 0; t < 16; ++t) {
    const int p = t & 1;
    // ---- phase 0: A mh0 + B nh0; issue next tile's stages ----
    if (t < 15) STAGE8(t + 1, p ^ 1);
#pragma unroll
    for (int m = 0; m < 4; ++m) LDA(af[m], m, p);
#pragma unroll
    for (int n = 0; n < 2; ++n) LDB(bf[n], n, p);
    __builtin_amdgcn_s_barrier();
    asm volatile("s_waitcnt lgkmcnt(0)" ::: "memory");
    __builtin_amdgcn_sched_barrier(0);
    MFMA16(0, 0);
    BARRIER_FENCE();
    // ---- phase 1: B nh1 ----
#pragma unroll
    for (int n = 0; n < 2; ++n) LDB(bf[n], n + 2, p);
    __builtin_amdgcn_s_barrier();
    asm volatile("s_waitcnt lgkmcnt(0)" ::: "memory");
    __builtin_amdgcn_sched_barrier(0);
    MFMA16(0, 2);
    BARRIER_FENCE();
    // ---- phase 2: A mh1 ----
#pragma unroll
    for (int m = 0; m < 4; ++m) LDA(af[m], m + 4, p);
    __builtin_amdgcn_s_barrier();
    asm volatile("s_waitcnt lgkmcnt(0)" ::: "memory");
    __builtin_amdgcn_sched_barrier(0);
    MFMA16(4, 2);
    BARRIER_FENCE();
    // ---- phase 3: B nh0 (reload) ----
#pragma unroll
    for (int n = 0; n < 2; ++n) LDB(bf[n], n, p);
    __builtin_amdgcn_s_barrier();
    asm volatile("s_waitcnt lgkmcnt(0)" ::: "memory");
    __builtin_amdgcn_sched_barrier(0);
    MFMA16(4, 0);
    if (t < 15) asm volatile("s_waitcnt vmcnt(0)" ::: "memory");  // next tile landed
    BARRIER_FENCE();
  }

  // ---- epilogue ----
  const int lr = lane & 15, lg4 = (lane >> 4) * 4;
#pragma unroll
  for (int m = 0; m < 8; ++m) {
#pragma unroll
    for (int n = 0; n < 4; ++n) {
      const int col = bn + wc * 64 + n * 16 + lr;
      float bv = bias[col];
      if (col < 1024) bv *= QSCALE;
      const int row0 = bm + wr * 128 + m * 16 + lg4;
      if (col < 2048) {
#pragma unroll
        for (int r = 0; r < 4; ++r)
          qkout[(size_t)(row0 + r) * 2048 + col] = f2bf(acc[m][n][r] + bv);
      } else {
        ushort4 vv;
        vv.x = f2bf(acc[m][n][0] + bv);
        vv.y = f2bf(acc[m][n][1] + bv);
        vv.z = f2bf(acc[m][n][2] + bv);
        vv.w = f2bf(acc[m][n][3] + bv);
        const size_t vidx = ((size_t)((row0 >> 11) * 1024 + (col - 2048))) * 2048 + (row0 & 2047);
        *reinterpret_cast<ushort4*>(&vTout[vidx]) = vv;
      }
    }
  }
#undef STAGE8
#undef LDA
#undef LDB
#undef BARRIER_FENCE
#undef MFMA16
}

// ---------------------------------------------------------------- GEMM (128x128, MODE 0): C = A @ Bt^T + bias, f32 out
__global__ __launch_bounds__(256) void gemm_bt0(const ushort* __restrict__ A,
                                                const ushort* __restrict__ Bt,
                                                const float* __restrict__ bias,
                                                float* __restrict__ out0,
                                                int Mdim, int Ndim, int K) {
  __shared__ __align__(16) ushort As[128 * 32];
  __shared__ __align__(16) ushort Bs[128 * 32];

  const int tid  = threadIdx.x;
  const int lane = tid & 63, wid = tid >> 6;
  const int wr = wid >> 1, wc = wid & 1;

  const int nx = gridDim.x;
  const int nwg = nx * gridDim.y;
  const int b0 = blockIdx.y * nx + blockIdx.x;
  const int nb = (b0 & 7) * (nwg >> 3) + (b0 >> 3);
  const int bm = (nb / nx) * 128, bn = (nb % nx) * 128;

  const int lrow = lane & 15, lk8 = (lane >> 4) * 8, lg4 = (lane >> 4) * 4;
  const int srow = tid >> 2;
  const int skk  = (tid & 3) * 8;

  f32x4 acc[4][4] = {};

  for (int k0 = 0; k0 < K; k0 += 32) {
#pragma unroll
    for (int j = 0; j < 2; ++j) {
      const ushort* ga = A  + (size_t)(bm + j * 64 + srow) * K + k0 + skk;
      const ushort* gb = Bt + (size_t)(bn + j * 64 + srow) * K + k0 + skk;
      gload_lds16(ga, (void*)&As[(j * 256 + wid * 64) * 8]);
      gload_lds16(gb, (void*)&Bs[(j * 256 + wid * 64) * 8]);
    }
    __syncthreads();

    bf16x8 af[4], bfv[4];
#pragma unroll
    for (int rb = 0; rb < 4; ++rb)
      af[rb] = *reinterpret_cast<const bf16x8*>(&As[(wr * 64 + rb * 16 + lrow) * 32 + lk8]);
#pragma unroll
    for (int cb = 0; cb < 4; ++cb)
      bfv[cb] = *reinterpret_cast<const bf16x8*>(&Bs[(wc * 64 + cb * 16 + lrow) * 32 + lk8]);
#pragma unroll
    for (int rb = 0; rb < 4; ++rb)
#pragma unroll
      for (int cb = 0; cb < 4; ++cb)
        acc[rb][cb] = __builtin_amdgcn_mfma_f32_16x16x32_bf16(af[rb], bfv[cb], acc[rb][cb], 0, 0, 0);
    __syncthreads();
  }

#pragma unroll
  for (int rb = 0; rb < 4; ++rb) {
#pragma unroll
    for (int cb = 0; cb < 4; ++cb) {
      const int col = bn + wc * 64 + cb * 16 + lrow;
      const float bv = bias[col];
      const int row0 = bm + wr * 64 + rb * 16 + lg4;
#pragma unroll
      for (int r = 0; r < 4; ++r)
        out0[(size_t)(row0 + r) * Ndim + col] = acc[rb][cb][r] + bv;
    }
  }
}

// ---------------------------------------------------------------- causal flash attention
// 8 waves x 32 q-rows = 256 q/block. Swapped QK^T: lane owns q = lane&31.
// qk: [M_][2048] bf16 (q | k). vT: [bh*64+d][2048] bf16 (s-contiguous). ctx: [M_][E_] bf16.
__global__ __launch_bounds__(512) void attn_causal(const ushort* __restrict__ qk,
                                                   const ushort* __restrict__ vT,
                                                   ushort* __restrict__ ctx) {
  __shared__ __align__(16) char lds[2][16384];  // [buf][ K 8KB | Vt 8KB ], XOR-swizzled rows

  const int tid = threadIdx.x;
  const int w = tid >> 6, lane = tid & 63;
  const int l31 = lane & 31, hi = lane >> 5;

  const int bid = blockIdx.x;
  const int bh = (bid & 7) * 8 + ((bid >> 3) & 7);  // 8 heads per XCD round
  const int g6 = bid >> 6;
  const int qb = (g6 < 4) ? (7 - g6) : (g6 - 4);    // pair (7,0),(6,1),(5,2),(4,3) per CU
  const int b = bh >> 4, h = bh & 15;
  const int qbase = qb * 256;
  const int tmax = 4 * qb + 3;
  const int qw = qbase + w * 32;
  const int q_g = qw + l31;
  const int my_tmax = (qw + 31) >> 6;

  // Q fragments (scale pre-folded into W_in q-rows)
  const ushort* qrow = qk + (size_t)(b * S_ + q_g) * 2048 + h * 64;
  bf16x8 qf[4];
#pragma unroll
  for (int st = 0; st < 4; ++st)
    qf[st] = *reinterpret_cast<const bf16x8*>(qrow + st * 16 + hi * 8);

  // staging: 512 threads x 16B = one 8KB tile each for K and Vt
  const int srow = tid >> 3;
  const int swz  = ((tid & 7) * 16) ^ ((srow & 7) << 4);
  const char* kbase = (const char*)qk + ((size_t)(b * S_ + srow) * 2048 + 1024 + h * 64) * 2 + swz;
  const char* vbase = (const char*)vT + ((size_t)(bh * 64 + srow) * 2048) * 2 + swz;

  f32x16 Ot0 = {}, Ot1 = {};
  float m_r = -__builtin_inff(), l_r = 0.f;

  const int kswz = ((l31 & 7) << 4);

#define STAGE(T, BUFI)                                                              \
  do {                                                                              \
    gload_lds16(kbase + (size_t)(T) * (64 * 2048 * 2), &lds[BUFI][w * 1024]);       \
    gload_lds16(vbase + (size_t)(T) * 128,             &lds[BUFI][8192 + w * 1024]);\
  } while (0)

  STAGE(0, 0);
  for (int t = 0; t <= tmax; ++t) {
    const int bufi = t & 1;
    if (t < tmax) {
      STAGE(t + 1, bufi ^ 1);
      asm volatile("s_waitcnt vmcnt(2)" ::: "memory");
    } else {
      asm volatile("s_waitcnt vmcnt(0)" ::: "memory");
    }
    __builtin_amdgcn_s_barrier();
    __builtin_amdgcn_sched_barrier(0);

    if (t <= my_tmax) {
      const char* Kt = &lds[bufi][0];
      const char* Vp = &lds[bufi][8192];

      // ---- S^T = K @ Q^T : lane owns column q = l31 ----
      f32x16 T0 = {}, T1 = {};
#pragma unroll
      for (int st = 0; st < 4; ++st) {
        const int cb = (st * 32 + hi * 16) ^ kswz;
        bf16x8 k0 = *(const bf16x8*)(Kt + l31 * 128 + cb);
        bf16x8 k1 = *(const bf16x8*)(Kt + (32 + l31) * 128 + cb);
        T0 = __builtin_amdgcn_mfma_f32_32x32x16_bf16(k0, qf[st], T0, 0, 0, 0);
        T1 = __builtin_amdgcn_mfma_f32_32x32x16_bf16(k1, qf[st], T1, 0, 0, 0);
      }

      // ---- mask + online softmax (lane-local; defer-max THR=8 in exp2 domain; max3 chain) ----
      float p[32];
      const bool needmask = (t * 64 + 63) > qw;
      const int kvb = t * 64 + 4 * hi;
#pragma unroll
      for (int g = 0; g < 4; ++g) {
#pragma unroll
        for (int j = 0; j < 4; ++j) {
          float v0 = T0[4 * g + j], v1 = T1[4 * g + j];
          if (needmask) {
            const int kv0 = kvb + 8 * g + j;
            v0 = (kv0      <= q_g) ? v0 : -__builtin_inff();
            v1 = (kv0 + 32 <= q_g) ? v1 : -__builtin_inff();
          }
          p[4 * g + j] = v0;
          p[16 + 4 * g + j] = v1;
        }
      }
      float pmax = p[0];
#pragma unroll
      for (int i = 1; i < 31; i += 2) pmax = fmaxf(fmaxf(pmax, p[i]), p[i + 1]);  // v_max3
      pmax = fmaxf(pmax, p[31]);
      pmax = fmaxf(pmax, __shfl_xor(pmax, 32));

      if (!__all(pmax - m_r <= 8.f)) {
        const float mn = fmaxf(m_r, pmax);
        const float sc = exp2f(m_r - mn);
        m_r = mn;
        l_r *= sc;
#pragma unroll
        for (int i = 0; i < 16; ++i) { Ot0[i] *= sc; Ot1[i] *= sc; }
      }
      float sum = 0.f;
#pragma unroll
      for (int i = 0; i < 32; ++i) { p[i] = exp2f(p[i] - m_r); sum += p[i]; }
      sum += __shfl_xor(sum, 32);
      l_r += sum;

      // ---- P -> bf16 B-fragments via shfl_xor(32) half-exchange; PV swapped: O^T col = q ----
#pragma unroll
      for (int ks = 0; ks < 4; ++ks) {
        const unsigned a = cvtpk(p[8 * ks + 0], p[8 * ks + 1]);
        const unsigned bq = cvtpk(p[8 * ks + 2], p[8 * ks + 3]);
        const unsigned c = cvtpk(p[8 * ks + 4], p[8 * ks + 5]);
        const unsigned d = cvtpk(p[8 * ks + 6], p[8 * ks + 7]);
        const unsigned x = hi ? a : c;
        const unsigned y = hi ? bq : d;
        const unsigned xp = (unsigned)__shfl_xor((int)x, 32);
        const unsigned yp = (unsigned)__shfl_xor((int)y, 32);
        union { unsigned u[4]; bf16x8 v; } pa;
        pa.u[0] = hi ? xp : a;   // k-elems 0,1
        pa.u[1] = hi ? yp : bq;  // k-elems 2,3
        pa.u[2] = hi ? c : xp;   // k-elems 4,5
        pa.u[3] = hi ? d : yp;   // k-elems 6,7
        const int cb = (ks * 32 + hi * 16) ^ kswz;
        bf16x8 v0 = *(const bf16x8*)(Vp + l31 * 128 + cb);
        bf16x8 v1 = *(const bf16x8*)(Vp + (32 + l31) * 128 + cb);
        Ot0 = __builtin_amdgcn_mfma_f32_32x32x16_bf16(v0, pa.v, Ot0, 0, 0, 0);
        Ot1 = __builtin_amdgcn_mfma_f32_32x32x16_bf16(v1, pa.v, Ot1, 0, 0, 0);
      }
    }
    __builtin_amdgcn_s_barrier();
    __builtin_amdgcn_sched_barrier(0);
  }

  // ---- epilogue: ctx[q][d] = O^T[d][q] / l ----
  const float inv = 1.0f / l_r;
  ushort* crow = ctx + (size_t)(b * S_ + q_g) * 1024 + h * 64;
#pragma unroll
  for (int g = 0; g < 4; ++g) {
#pragma unroll
    for (int jp = 0; jp < 2; ++jp) {
      const int d0 = 2 * jp + 8 * g + 4 * hi;
      const int r = 4 * g + 2 * jp;
      *(unsigned*)(crow + d0)      = cvtpk(Ot0[r] * inv, Ot0[r + 1] * inv);
      *(unsigned*)(crow + 32 + d0) = cvtpk(Ot1[r] * inv, Ot1[r + 1] * inv);
    }
  }
#undef STAGE
}

// ---------------------------------------------------------------- residual + LayerNorm
__global__ __launch_bounds__(256) void resid_ln(const float* __restrict__ x,
                                                const float* __restrict__ ao,
                                                const float* __restrict__ gamma,
                                                const float* __restrict__ beta,
                                                float* __restrict__ out) {
  const int row = blockIdx.x;
  const int tid = threadIdx.x;
  const size_t base = (size_t)row * E_;

  float4 xv = reinterpret_cast<const float4*>(x + base)[tid];
  float4 av = reinterpret_cast<const float4*>(ao + base)[tid];
  const float v0 = xv.x + av.x, v1 = xv.y + av.y, v2 = xv.z + av.z, v3 = xv.w + av.w;
  float s  = v0 + v1 + v2 + v3;
  float s2 = v0 * v0 + v1 * v1 + v2 * v2 + v3 * v3;
#pragma unroll
  for (int off = 32; off >= 1; off >>= 1) {
    s  += __shfl_xor(s, off);
    s2 += __shfl_xor(s2, off);
  }
  __shared__ float red[8];
  const int wid = tid >> 6, lane = tid & 63;
  if (lane == 0) { red[wid] = s; red[4 + wid] = s2; }
  __syncthreads();
  s  = red[0] + red[1] + red[2] + red[3];
  s2 = red[4] + red[5] + red[6] + red[7];
  const float mu  = s * (1.f / E_);
  const float var = s2 * (1.f / E_) - mu * mu;
  const float rsd = rsqrtf(var + 1e-5f);

  float4 gv = reinterpret_cast<const float4*>(gamma)[tid];
  float4 bv = reinterpret_cast<const float4*>(beta)[tid];
  float4 ov;
  ov.x = (v0 - mu) * rsd * gv.x + bv.x;
  ov.y = (v1 - mu) * rsd * gv.y + bv.y;
  ov.z = (v2 - mu) * rsd * gv.z + bv.z;
  ov.w = (v3 - mu) * rsd * gv.w + bv.w;
  reinterpret_cast<float4*>(out + base)[tid] = ov;
}

// ---------------------------------------------------------------- launch
extern "C" void kernel_launch(void* const* d_in, const int* in_sizes, int n_in,
                              void* d_out, int out_size, void* d_ws, size_t ws_size,
                              hipStream_t stream) {
  (void)in_sizes; (void)n_in; (void)out_size; (void)ws_size;
  const float* x     = (const float*)d_in[0];
  const float* w_in  = (const float*)d_in[1];
  const float* b_in  = (const float*)d_in[2];
  const float* w_out = (const float*)d_in[3];
  const float* b_out = (const float*)d_in[4];
  const float* gamma = (const float*)d_in[5];
  const float* beta  = (const float*)d_in[6];
  float* out = (float*)d_out;

  char* ws = (char*)d_ws;
  ushort* xb    = (ushort*)(ws);                          // 16 MB
  ushort* winb  = (ushort*)(ws + 16777216);               // 6 MB
  ushort* woutb = (ushort*)(ws + 23068672);               // 2 MB
  ushort* qkb   = (ushort*)(ws + 25165824);               // 32 MB  [8192][2048]
  ushort* vTb   = (ushort*)(ws + 58720256);               // 16 MB  [4096][2048]
  ushort* ctxb  = (ushort*)(ws + 75497472);               // 16 MB
  float*  ao    = (float*)(ws + 92274688);                // 32 MB  -> total 120 MB

  cvt_f32_bf16<<<dim3((M_ * E_) / 4 / 256), 256, 0, stream>>>(x, xb, (M_ * E_) / 4, 0, 1.f);
  cvt_f32_bf16<<<dim3((E3_ * E_) / 4 / 256), 256, 0, stream>>>(w_in, winb, (E3_ * E_) / 4,
                                                               (E_ * E_) / 4, QSCALE);
  cvt_f32_bf16<<<dim3((E_ * E_) / 4 / 256), 256, 0, stream>>>(w_out, woutb, (E_ * E_) / 4, 0, 1.f);

  gemm_qkv_256<<<dim3(384), 512, 0, stream>>>(xb, winb, b_in, qkb, vTb);
  attn_causal<<<dim3(512), 512, 0, stream>>>(qkb, vTb, ctxb);
  gemm_bt0<<<dim3(E_ / 128, M_ / 128), 256, 0, stream>>>(ctxb, woutb, b_out, ao, M_, E_, E_);
  resid_ln<<<dim3(M_), 256, 0, stream>>>(x, ao, gamma, beta, out);
}

// Round 8
// 211.987 us; speedup vs baseline: 1.0439x; 1.0439x over previous
//
#include <hip/hip_runtime.h>
#include <hip/hip_bf16.h>
#include <stdint.h>

// Problem constants
#define B_   4
#define S_   2048
#define E_   1024
#define H_   16
#define D_   64
#define M_   (B_ * S_)     // 8192 rows
#define E3_  (3 * E_)      // 3072

#define QSCALE 0.18033688011112042f  // 0.125 * log2(e)

typedef __bf16 bf16_t;
typedef bf16_t bf16x8 __attribute__((ext_vector_type(8)));
typedef float  f32x4  __attribute__((ext_vector_type(4)));
typedef float  f32x16 __attribute__((ext_vector_type(16)));

__device__ __forceinline__ ushort f2bf(float f) {
  union { float f; uint32_t u; } v; v.f = f;
  uint32_t r = v.u + 0x7fffu + ((v.u >> 16) & 1u);
  return (ushort)(r >> 16);
}

__device__ __forceinline__ unsigned cvtpk(float lo, float hi_) {
  unsigned d;
  asm("v_cvt_pk_bf16_f32 %0, %1, %2" : "=v"(d) : "v"(lo), "v"(hi_));
  return d;
}

__device__ __forceinline__ void gload_lds16(const void* g, void* l) {
  __builtin_amdgcn_global_load_lds((const __attribute__((address_space(1))) void*)g,
                                   (__attribute__((address_space(3))) void*)l,
                                   16, 0, 0);
}

// ---------------------------------------------------------------- cvt f32->bf16 (optional row-scale)
__global__ __launch_bounds__(256) void cvt_f32_bf16(const float* __restrict__ in,
                                                    ushort* __restrict__ out, int n4,
                                                    int scale_row4, float scale) {
  int i = blockIdx.x * blockDim.x + threadIdx.x;
  if (i < n4) {
    float4 v = reinterpret_cast<const float4*>(in)[i];
    if (i < scale_row4) { v.x *= scale; v.y *= scale; v.z *= scale; v.w *= scale; }
    ushort4 o;
    o.x = f2bf(v.x); o.y = f2bf(v.y); o.z = f2bf(v.z); o.w = f2bf(v.w);
    reinterpret_cast<ushort4*>(out)[i] = o;
  }
}

// ---------------------------------------------------------------- QKV GEMM, 128x256 tile, 3-ring LDS, counted vmcnt
// A: [M_][1024] bf16. Bt: [3072][1024] bf16. Epilogue: cols<2048 -> qk[row][2048] bf16;
// cols>=2048 -> vT[(b*1024 + col-2048)][2048] (s-contiguous); q-bias scaled by QSCALE.
// 512 thr = 8 waves (2M x 4N); wave-tile 64x64; BK=64; LDS 3 x 48KB ring (A 16KB + B 32KB);
// prefetch 2 tiles ahead; per tile 2 phases, vmcnt(6) at tile boundary (never 0 until drain).
// Grid 768 = 64 x 12 tiles -> exactly 3 blocks/CU; XCD-bijective swizzle (768%8==0).
__global__ __launch_bounds__(512) void gemm_qkv_8ph(const ushort* __restrict__ A,
                                                    const ushort* __restrict__ Bt,
                                                    const float* __restrict__ bias,
                                                    ushort* __restrict__ qkout,
                                                    ushort* __restrict__ vTout) {
  __shared__ __align__(16) char lds[3][49152];  // ring: [A 16KB | B 32KB]

  const int tid = threadIdx.x;
  const int lane = tid & 63, wid = tid >> 6;
  const int wr = wid >> 2, wc = wid & 3;        // 2M x 4N

  const int b0 = blockIdx.x;
  const int nb = (b0 & 7) * 96 + (b0 >> 3);     // XCD-contiguous
  const int bm = (nb / 12) * 128;
  const int bn = (nb % 12) * 256;

  // ---- staging addressing (pre-swizzled source, linear LDS dest) ----
  const int l8 = lane >> 3;                     // 0..7
  const int sw = (lane & 7) ^ l8;               // source 16B slot
  const ushort* aS = A  + (size_t)(bm + wid * 16 + l8) * 1024 + sw * 8;  // +j*8 rows, j=0,1
  const ushort* bS = Bt + (size_t)(bn + wid * 32 + l8) * 1024 + sw * 8;  // +j*8 rows, j=0..3

#define STAGE_A(T, BUF, J) \
  gload_lds16(aS + (size_t)(T) * 64 + (J) * 8 * 1024, (void*)((BUF) + (wid * 2 + (J)) * 1024))
#define STAGE_B(T, BUF, J) \
  gload_lds16(bS + (size_t)(T) * 64 + (J) * 8 * 1024, (void*)((BUF) + 16384 + (wid * 4 + (J)) * 1024))

  // ---- fragment read addressing (swizzled 16B slots; swizzle is lane-only here) ----
  const int lr15 = lane & 15;
  const int ksub = lane >> 4;                   // 0..3
  const int slot0 = ((ksub + 0) ^ (lr15 & 7)) * 16;  // kh=0
  const int slot1 = ((ksub + 4) ^ (lr15 & 7)) * 16;  // kh=1
  const int arow_b = (wr * 64 + lr15) * 128;
  const int brow_b = (wc * 64 + lr15) * 128;

#define LDA_ALL(BUF)                                                              \
  do {                                                                            \
    _Pragma("unroll")                                                             \
    for (int m = 0; m < 4; ++m) {                                                 \
      af[m][0] = *(const bf16x8*)((BUF) + arow_b + m * 2048 + slot0);             \
      af[m][1] = *(const bf16x8*)((BUF) + arow_b + m * 2048 + slot1);             \
    }                                                                             \
  } while (0)
#define LDB2(BUF, NB)                                                             \
  do {                                                                            \
    _Pragma("unroll")                                                             \
    for (int n = 0; n < 2; ++n) {                                                 \
      bfr[n][0] = *(const bf16x8*)((BUF) + 16384 + brow_b + ((NB) + n) * 2048 + slot0); \
      bfr[n][1] = *(const bf16x8*)((BUF) + 16384 + brow_b + ((NB) + n) * 2048 + slot1); \
    }                                                                             \
  } while (0)
#define MFMA16(NB)                                                                \
  do {                                                                            \
    __builtin_amdgcn_s_setprio(1);                                                \
    _Pragma("unroll")                                                             \
    for (int m = 0; m < 4; ++m)                                                   \
      _Pragma("unroll")                                                           \
      for (int n = 0; n < 2; ++n)                                                 \
        _Pragma("unroll")                                                         \
        for (int kh = 0; kh < 2; ++kh)                                            \
          acc[m][(NB) + n] = __builtin_amdgcn_mfma_f32_16x16x32_bf16(             \
              af[m][kh], bfr[n][kh], acc[m][(NB) + n], 0, 0, 0);                  \
    __builtin_amdgcn_s_setprio(0);                                                \
  } while (0)

  f32x4 acc[4][4] = {};
  bf16x8 af[4][2], bfr[2][2];

  char* buf0 = &lds[0][0];   // tile t
  char* buf1 = &lds[1][0];   // tile t+1
  char* buf2 = &lds[2][0];   // staging tile t+2

  // ---- prologue: stage t0, t1 ----
  STAGE_A(0, buf0, 0); STAGE_A(0, buf0, 1);
  STAGE_B(0, buf0, 0); STAGE_B(0, buf0, 1); STAGE_B(0, buf0, 2); STAGE_B(0, buf0, 3);
  STAGE_A(1, buf1, 0); STAGE_A(1, buf1, 1);
  STAGE_B(1, buf1, 0); STAGE_B(1, buf1, 1); STAGE_B(1, buf1, 2); STAGE_B(1, buf1, 3);
  asm volatile("s_waitcnt vmcnt(6)" ::: "memory");   // t0 landed (collective after barrier)
  __builtin_amdgcn_s_barrier();
  __builtin_amdgcn_sched_barrier(0);

  for (int t = 0; t < 16; ++t) {
    // ---- phase 0: stage 3 of tile t+2; read all A + B n0-1; MFMA n0-1 ----
    if (t < 14) { STAGE_A(t + 2, buf2, 0); STAGE_A(t + 2, buf2, 1); STAGE_B(t + 2, buf2, 0); }
    LDA_ALL(buf0);
    LDB2(buf0, 0);
    __builtin_amdgcn_s_barrier();
    asm volatile("s_waitcnt lgkmcnt(0)" ::: "memory");
    __builtin_amdgcn_sched_barrier(0);
    MFMA16(0);
    __builtin_amdgcn_s_barrier();
    __builtin_amdgcn_sched_barrier(0);
    // ---- phase 1: stage 3 of tile t+2; read B n2-3; MFMA n2-3; counted wait ----
    if (t < 14) { STAGE_B(t + 2, buf2, 1); STAGE_B(t + 2, buf2, 2); STAGE_B(t + 2, buf2, 3); }
    LDB2(buf0, 2);
    __builtin_amdgcn_s_barrier();
    asm volatile("s_waitcnt lgkmcnt(0)" ::: "memory");
    __builtin_amdgcn_sched_barrier(0);
    MFMA16(2);
    if (t < 14) asm volatile("s_waitcnt vmcnt(6)" ::: "memory");       // t+1 landed
    else if (t == 14) asm volatile("s_waitcnt vmcnt(0)" ::: "memory"); // final drain
    __builtin_amdgcn_s_barrier();
    __builtin_amdgcn_sched_barrier(0);
    // ---- rotate ring ----
    char* tmp = buf0; buf0 = buf1; buf1 = buf2; buf2 = tmp;
  }

  // ---- epilogue ----
#pragma unroll
  for (int m = 0; m < 4; ++m) {
#pragma unroll
    for (int n = 0; n < 4; ++n) {
      const int col = bn + wc * 64 + n * 16 + lr15;
      float bv = bias[col];
      if (col < 1024) bv *= QSCALE;
      const int row0 = bm + wr * 64 + m * 16 + ksub * 4;
      if (col < 2048) {
#pragma unroll
        for (int r = 0; r < 4; ++r)
          qkout[(size_t)(row0 + r) * 2048 + col] = f2bf(acc[m][n][r] + bv);
      } else {
        ushort4 vv;
        vv.x = f2bf(acc[m][n][0] + bv);
        vv.y = f2bf(acc[m][n][1] + bv);
        vv.z = f2bf(acc[m][n][2] + bv);
        vv.w = f2bf(acc[m][n][3] + bv);
        const size_t vidx = ((size_t)((row0 >> 11) * 1024 + (col - 2048))) * 2048 + (row0 & 2047);
        *reinterpret_cast<ushort4*>(&vTout[vidx]) = vv;
      }
    }
  }
#undef STAGE_A
#undef STAGE_B
#undef LDA_ALL
#undef LDB2
#undef MFMA16
}

// ---------------------------------------------------------------- GEMM (128x128, MODE 0): C = A @ Bt^T + bias, f32 out
__global__ __launch_bounds__(256) void gemm_bt0(const ushort* __restrict__ A,
                                                const ushort* __restrict__ Bt,
                                                const float* __restrict__ bias,
                                                float* __restrict__ out0,
                                                int Mdim, int Ndim, int K) {
  __shared__ __align__(16) ushort As[128 * 32];
  __shared__ __align__(16) ushort Bs[128 * 32];

  const int tid  = threadIdx.x;
  const int lane = tid & 63, wid = tid >> 6;
  const int wr = wid >> 1, wc = wid & 1;

  const int nx = gridDim.x;
  const int nwg = nx * gridDim.y;
  const int b0 = blockIdx.y * nx + blockIdx.x;
  const int nb = (b0 & 7) * (nwg >> 3) + (b0 >> 3);
  const int bm = (nb / nx) * 128, bn = (nb % nx) * 128;

  const int lrow = lane & 15, lk8 = (lane >> 4) * 8, lg4 = (lane >> 4) * 4;
  const int srow = tid >> 2;
  const int skk  = (tid & 3) * 8;

  f32x4 acc[4][4] = {};

  for (int k0 = 0; k0 < K; k0 += 32) {
#pragma unroll
    for (int j = 0; j < 2; ++j) {
      const ushort* ga = A  + (size_t)(bm + j * 64 + srow) * K + k0 + skk;
      const ushort* gb = Bt + (size_t)(bn + j * 64 + srow) * K + k0 + skk;
      gload_lds16(ga, (void*)&As[(j * 256 + wid * 64) * 8]);
      gload_lds16(gb, (void*)&Bs[(j * 256 + wid * 64) * 8]);
    }
    __syncthreads();

    bf16x8 af[4], bfv[4];
#pragma unroll
    for (int rb = 0; rb < 4; ++rb)
      af[rb] = *reinterpret_cast<const bf16x8*>(&As[(wr * 64 + rb * 16 + lrow) * 32 + lk8]);
#pragma unroll
    for (int cb = 0; cb < 4; ++cb)
      bfv[cb] = *reinterpret_cast<const bf16x8*>(&Bs[(wc * 64 + cb * 16 + lrow) * 32 + lk8]);
#pragma unroll
    for (int rb = 0; rb < 4; ++rb)
#pragma unroll
      for (int cb = 0; cb < 4; ++cb)
        acc[rb][cb] = __builtin_amdgcn_mfma_f32_16x16x32_bf16(af[rb], bfv[cb], acc[rb][cb], 0, 0, 0);
    __syncthreads();
  }

#pragma unroll
  for (int rb = 0; rb < 4; ++rb) {
#pragma unroll
    for (int cb = 0; cb < 4; ++cb) {
      const int col = bn + wc * 64 + cb * 16 + lrow;
      const float bv = bias[col];
      const int row0 = bm + wr * 64 + rb * 16 + lg4;
#pragma unroll
      for (int r = 0; r < 4; ++r)
        out0[(size_t)(row0 + r) * Ndim + col] = acc[rb][cb][r] + bv;
    }
  }
}

// ---------------------------------------------------------------- causal flash attention
// 8 waves x 32 q-rows = 256 q/block. Swapped QK^T: lane owns q = lane&31.
// qk: [M_][2048] bf16 (q | k). vT: [bh*64+d][2048] bf16 (s-contiguous). ctx: [M_][E_] bf16.
__global__ __launch_bounds__(512) void attn_causal(const ushort* __restrict__ qk,
                                                   const ushort* __restrict__ vT,
                                                   ushort* __restrict__ ctx) {
  __shared__ __align__(16) char lds[2][16384];  // [buf][ K 8KB | Vt 8KB ], XOR-swizzled rows

  const int tid = threadIdx.x;
  const int w = tid >> 6, lane = tid & 63;
  const int l31 = lane & 31, hi = lane >> 5;

  const int bid = blockIdx.x;
  const int bh = (bid & 7) * 8 + ((bid >> 3) & 7);  // 8 heads per XCD round
  const int g6 = bid >> 6;
  const int qb = (g6 < 4) ? (7 - g6) : (g6 - 4);    // pair (7,0),(6,1),(5,2),(4,3) per CU
  const int b = bh >> 4, h = bh & 15;
  const int qbase = qb * 256;
  const int tmax = 4 * qb + 3;
  const int qw = qbase + w * 32;
  const int q_g = qw + l31;
  const int my_tmax = (qw + 31) >> 6;

  // Q fragments (scale pre-folded into W_in q-rows)
  const ushort* qrow = qk + (size_t)(b * S_ + q_g) * 2048 + h * 64;
  bf16x8 qf[4];
#pragma unroll
  for (int st = 0; st < 4; ++st)
    qf[st] = *reinterpret_cast<const bf16x8*>(qrow + st * 16 + hi * 8);

  // staging: 512 threads x 16B = one 8KB tile each for K and Vt
  const int srow = tid >> 3;
  const int swz  = ((tid & 7) * 16) ^ ((srow & 7) << 4);
  const char* kbase = (const char*)qk + ((size_t)(b * S_ + srow) * 2048 + 1024 + h * 64) * 2 + swz;
  const char* vbase = (const char*)vT + ((size_t)(bh * 64 + srow) * 2048) * 2 + swz;

  f32x16 Ot0 = {}, Ot1 = {};
  float m_r = -__builtin_inff(), l_r = 0.f;

  const int kswz = ((l31 & 7) << 4);

#define STAGE(T, BUFI)                                                              \
  do {                                                                              \
    gload_lds16(kbase + (size_t)(T) * (64 * 2048 * 2), &lds[BUFI][w * 1024]);       \
    gload_lds16(vbase + (size_t)(T) * 128,             &lds[BUFI][8192 + w * 1024]);\
  } while (0)

  STAGE(0, 0);
  for (int t = 0; t <= tmax; ++t) {
    const int bufi = t & 1;
    if (t < tmax) {
      STAGE(t + 1, bufi ^ 1);
      asm volatile("s_waitcnt vmcnt(2)" ::: "memory");
    } else {
      asm volatile("s_waitcnt vmcnt(0)" ::: "memory");
    }
    __builtin_amdgcn_s_barrier();
    __builtin_amdgcn_sched_barrier(0);

    if (t <= my_tmax) {
      const char* Kt = &lds[bufi][0];
      const char* Vp = &lds[bufi][8192];

      // ---- S^T = K @ Q^T : lane owns column q = l31 ----
      f32x16 T0 = {}, T1 = {};
#pragma unroll
      for (int st = 0; st < 4; ++st) {
        const int cb = (st * 32 + hi * 16) ^ kswz;
        bf16x8 k0 = *(const bf16x8*)(Kt + l31 * 128 + cb);
        bf16x8 k1 = *(const bf16x8*)(Kt + (32 + l31) * 128 + cb);
        T0 = __builtin_amdgcn_mfma_f32_32x32x16_bf16(k0, qf[st], T0, 0, 0, 0);
        T1 = __builtin_amdgcn_mfma_f32_32x32x16_bf16(k1, qf[st], T1, 0, 0, 0);
      }

      // ---- mask + online softmax (lane-local; defer-max THR=8 in exp2 domain; max3 chain) ----
      float p[32];
      const bool needmask = (t * 64 + 63) > qw;
      const int kvb = t * 64 + 4 * hi;
#pragma unroll
      for (int g = 0; g < 4; ++g) {
#pragma unroll
        for (int j = 0; j < 4; ++j) {
          float v0 = T0[4 * g + j], v1 = T1[4 * g + j];
          if (needmask) {
            const int kv0 = kvb + 8 * g + j;
            v0 = (kv0      <= q_g) ? v0 : -__builtin_inff();
            v1 = (kv0 + 32 <= q_g) ? v1 : -__builtin_inff();
          }
          p[4 * g + j] = v0;
          p[16 + 4 * g + j] = v1;
        }
      }
      float pmax = p[0];
#pragma unroll
      for (int i = 1; i < 31; i += 2) pmax = fmaxf(fmaxf(pmax, p[i]), p[i + 1]);  // v_max3
      pmax = fmaxf(pmax, p[31]);
      pmax = fmaxf(pmax, __shfl_xor(pmax, 32));

      if (!__all(pmax - m_r <= 8.f)) {
        const float mn = fmaxf(m_r, pmax);
        const float sc = exp2f(m_r - mn);
        m_r = mn;
        l_r *= sc;
#pragma unroll
        for (int i = 0; i < 16; ++i) { Ot0[i] *= sc; Ot1[i] *= sc; }
      }
      float sum = 0.f;
#pragma unroll
      for (int i = 0; i < 32; ++i) { p[i] = exp2f(p[i] - m_r); sum += p[i]; }
      sum += __shfl_xor(sum, 32);
      l_r += sum;

      // ---- P -> bf16 B-fragments via shfl_xor(32) half-exchange; PV swapped: O^T col = q ----
#pragma unroll
      for (int ks = 0; ks < 4; ++ks) {
        const unsigned a = cvtpk(p[8 * ks + 0], p[8 * ks + 1]);
        const unsigned bq = cvtpk(p[8 * ks + 2], p[8 * ks + 3]);
        const unsigned c = cvtpk(p[8 * ks + 4], p[8 * ks + 5]);
        const unsigned d = cvtpk(p[8 * ks + 6], p[8 * ks + 7]);
        const unsigned x = hi ? a : c;
        const unsigned y = hi ? bq : d;
        const unsigned xp = (unsigned)__shfl_xor((int)x, 32);
        const unsigned yp = (unsigned)__shfl_xor((int)y, 32);
        union { unsigned u[4]; bf16x8 v; } pa;
        pa.u[0] = hi ? xp : a;   // k-elems 0,1
        pa.u[1] = hi ? yp : bq;  // k-elems 2,3
        pa.u[2] = hi ? c : xp;   // k-elems 4,5
        pa.u[3] = hi ? d : yp;   // k-elems 6,7
        const int cb = (ks * 32 + hi * 16) ^ kswz;
        bf16x8 v0 = *(const bf16x8*)(Vp + l31 * 128 + cb);
        bf16x8 v1 = *(const bf16x8*)(Vp + (32 + l31) * 128 + cb);
        Ot0 = __builtin_amdgcn_mfma_f32_32x32x16_bf16(v0, pa.v, Ot0, 0, 0, 0);
        Ot1 = __builtin_amdgcn_mfma_f32_32x32x16_bf16(v1, pa.v, Ot1, 0, 0, 0);
      }
    }
    __builtin_amdgcn_s_barrier();
    __builtin_amdgcn_sched_barrier(0);
  }

  // ---- epilogue: ctx[q][d] = O^T[d][q] / l ----
  const float inv = 1.0f / l_r;
  ushort* crow = ctx + (size_t)(b * S_ + q_g) * 1024 + h * 64;
#pragma unroll
  for (int g = 0; g < 4; ++g) {
#pragma unroll
    for (int jp = 0; jp < 2; ++jp) {
      const int d0 = 2 * jp + 8 * g + 4 * hi;
      const int r = 4 * g + 2 * jp;
      *(unsigned*)(crow + d0)      = cvtpk(Ot0[r] * inv, Ot0[r + 1] * inv);
      *(unsigned*)(crow + 32 + d0) = cvtpk(Ot1[r] * inv, Ot1[r + 1] * inv);
    }
  }
#undef STAGE
}

// ---------------------------------------------------------------- residual + LayerNorm
__global__ __launch_bounds__(256) void resid_ln(const float* __restrict__ x,
                                                const float* __restrict__ ao,
                                                const float* __restrict__ gamma,
                                                const float* __restrict__ beta,
                                                float* __restrict__ out) {
  const int row = blockIdx.x;
  const int tid = threadIdx.x;
  const size_t base = (size_t)row * E_;

  float4 xv = reinterpret_cast<const float4*>(x + base)[tid];
  float4 av = reinterpret_cast<const float4*>(ao + base)[tid];
  const float v0 = xv.x + av.x, v1 = xv.y + av.y, v2 = xv.z + av.z, v3 = xv.w + av.w;
  float s  = v0 + v1 + v2 + v3;
  float s2 = v0 * v0 + v1 * v1 + v2 * v2 + v3 * v3;
#pragma unroll
  for (int off = 32; off >= 1; off >>= 1) {
    s  += __shfl_xor(s, off);
    s2 += __shfl_xor(s2, off);
  }
  __shared__ float red[8];
  const int wid = tid >> 6, lane = tid & 63;
  if (lane == 0) { red[wid] = s; red[4 + wid] = s2; }
  __syncthreads();
  s  = red[0] + red[1] + red[2] + red[3];
  s2 = red[4] + red[5] + red[6] + red[7];
  const float mu  = s * (1.f / E_);
  const float var = s2 * (1.f / E_) - mu * mu;
  const float rsd = rsqrtf(var + 1e-5f);

  float4 gv = reinterpret_cast<const float4*>(gamma)[tid];
  float4 bv = reinterpret_cast<const float4*>(beta)[tid];
  float4 ov;
  ov.x = (v0 - mu) * rsd * gv.x + bv.x;
  ov.y = (v1 - mu) * rsd * gv.y + bv.y;
  ov.z = (v2 - mu) * rsd * gv.z + bv.z;
  ov.w = (v3 - mu) * rsd * gv.w + bv.w;
  reinterpret_cast<float4*>(out + base)[tid] = ov;
}

// ---------------------------------------------------------------- launch
extern "C" void kernel_launch(void* const* d_in, const int* in_sizes, int n_in,
                              void* d_out, int out_size, void* d_ws, size_t ws_size,
                              hipStream_t stream) {
  (void)in_sizes; (void)n_in; (void)out_size; (void)ws_size;
  const float* x     = (const float*)d_in[0];
  const float* w_in  = (const float*)d_in[1];
  const float* b_in  = (const float*)d_in[2];
  const float* w_out = (const float*)d_in[3];
  const float* b_out = (const float*)d_in[4];
  const float* gamma = (const float*)d_in[5];
  const float* beta  = (const float*)d_in[6];
  float* out = (float*)d_out;

  char* ws = (char*)d_ws;
  ushort* xb    = (ushort*)(ws);                          // 16 MB
  ushort* winb  = (ushort*)(ws + 16777216);               // 6 MB
  ushort* woutb = (ushort*)(ws + 23068672);               // 2 MB
  ushort* qkb   = (ushort*)(ws + 25165824);               // 32 MB  [8192][2048]
  ushort* vTb   = (ushort*)(ws + 58720256);               // 16 MB  [4096][2048]
  ushort* ctxb  = (ushort*)(ws + 75497472);               // 16 MB
  float*  ao    = (float*)(ws + 92274688);                // 32 MB  -> total 120 MB

  cvt_f32_bf16<<<dim3((M_ * E_) / 4 / 256), 256, 0, stream>>>(x, xb, (M_ * E_) / 4, 0, 1.f);
  cvt_f32_bf16<<<dim3((E3_ * E_) / 4 / 256), 256, 0, stream>>>(w_in, winb, (E3_ * E_) / 4,
                                                               (E_ * E_) / 4, QSCALE);
  cvt_f32_bf16<<<dim3((E_ * E_) / 4 / 256), 256, 0, stream>>>(w_out, woutb, (E_ * E_) / 4, 0, 1.f);

  gemm_qkv_8ph<<<dim3(768), 512, 0, stream>>>(xb, winb, b_in, qkb, vTb);
  attn_causal<<<dim3(512), 512, 0, stream>>>(qkb, vTb, ctxb);
  gemm_bt0<<<dim3(E_ / 128, M_ / 128), 256, 0, stream>>>(ctxb, woutb, b_out, ao, M_, E_, E_);
  resid_ln<<<dim3(M_), 256, 0, stream>>>(x, ao, gamma, beta, out);
}